// Round 3
// baseline (1573.182 us; speedup 1.0000x reference)
//
#include <hip/hip_runtime.h>
#include <hip/hip_bf16.h>
#include <stdint.h>

#define N_AUTHORS 50000
#define N_PAPERS  100000
#define N_TOT     150000
#define N_ROWPAD  150016      // rows padded to multiple of 64 for GEMM tiles
#define N_SCAN    150528      // 147 * 1024, scan domain
#define DIM       128
#define E_EDGES   2400000
#define OUT_STRIDE 512

// ---- workspace layout (bytes) ----
#define EGO_OFF   0ULL                                   // bf16 [150016][128]  = 38,404,096
#define SIDE_OFF  (EGO_OFF  + 38404096ULL)               // f32  [150016][128]  = 76,808,192
#define COLP_OFF  (SIDE_OFF + 76808192ULL)               // int  [E]            =  9,600,000
#define VALP_OFF  (COLP_OFF + 9600000ULL)                // f32  [E]            =  9,600,000
#define RPTR_OFF  (VALP_OFF + 9600000ULL)                // int  [150784]       =    603,136
#define CNT_OFF   (RPTR_OFF + 603136ULL)                 // int  [150528]       =    602,112
#define FILL_OFF  (CNT_OFF  + 602112ULL)                 // int  [150528]       =    602,112
#define BSUM_OFF  (FILL_OFF + 602112ULL)                 // int  [256]          =      1,024
#define W1B_OFF   (BSUM_OFF + 1024ULL)                   // bf16 [3][128][128]  =     98,304
#define W2B_OFF   (W1B_OFF  + 98304ULL)                  // bf16 [3][128][128]  =     98,304
// total ~136.5 MB

typedef __attribute__((ext_vector_type(8))) __bf16 bf16x8;
typedef __attribute__((ext_vector_type(4))) float  f32x4;

__device__ __forceinline__ unsigned short f2bf(float f) {
    union { float f; unsigned int i; } v; v.f = f;
    unsigned int x = v.i;
    return (unsigned short)((x + 0x7FFFu + ((x >> 16) & 1u)) >> 16);
}
__device__ __forceinline__ unsigned int pack2(float a, float b) {
    return (unsigned int)f2bf(a) | ((unsigned int)f2bf(b) << 16);
}

// ---- convert weights f32 -> bf16 (3*128*128 each) ----
__global__ void k_cvt_w(const float* __restrict__ W1, const float* __restrict__ W2,
                        unsigned short* __restrict__ w1b, unsigned short* __restrict__ w2b) {
    int t = blockIdx.x * blockDim.x + threadIdx.x;
    if (t < 3 * DIM * DIM) {
        w1b[t] = f2bf(W1[t]);
        w2b[t] = f2bf(W2[t]);
    }
}

// ---- build ego = concat(author, paper) as bf16; write layer-0 output chunk (f32 verbatim) ----
__global__ void k_init(const float* __restrict__ author,
                       const float* __restrict__ paper,
                       unsigned short* __restrict__ ego,
                       float* __restrict__ out) {
    int t = blockIdx.x * blockDim.x + threadIdx.x;   // one thread per 8 elements
    if (t >= N_TOT * (DIM / 8)) return;
    int row = t >> 4;        // 16 chunks of 8 per row
    int c   = t & 15;
    const float* src = (row < N_AUTHORS) ? (author + (size_t)row * DIM)
                                         : (paper + (size_t)(row - N_AUTHORS) * DIM);
    float4 a = *(const float4*)(src + c * 8);
    float4 b = *(const float4*)(src + c * 8 + 4);
    // exact f32 copy into output chunk 0
    float* drow = out + (size_t)row * OUT_STRIDE + c * 8;
    *(float4*)(drow)     = a;
    *(float4*)(drow + 4) = b;
    // bf16 internal copy
    uint4 v;
    v.x = pack2(a.x, a.y);
    v.y = pack2(a.z, a.w);
    v.z = pack2(b.x, b.y);
    v.w = pack2(b.z, b.w);
    *(uint4*)(ego + (size_t)row * DIM + c * 8) = v;
}

// ---- CSR build ----
__global__ void k_hist(const int* __restrict__ rows, int* __restrict__ cnt) {
    int t = blockIdx.x * blockDim.x + threadIdx.x;
    if (t < E_EDGES) atomicAdd(&cnt[rows[t]], 1);
}

__global__ void k_scan_blocks(const int* __restrict__ cnt, int* __restrict__ rptr,
                              int* __restrict__ bsum) {
    __shared__ int sm[1024];
    int t = threadIdx.x;
    int i = blockIdx.x * 1024 + t;
    int x = cnt[i];
    sm[t] = x;
    __syncthreads();
    for (int off = 1; off < 1024; off <<= 1) {
        int y = (t >= off) ? sm[t - off] : 0;
        __syncthreads();
        sm[t] += y;
        __syncthreads();
    }
    rptr[i] = sm[t] - x;                 // exclusive within block
    if (t == 1023) bsum[blockIdx.x] = sm[1023];
}

__global__ void k_scan_top(int* __restrict__ bsum) {
    __shared__ int sm[256];
    int t = threadIdx.x;
    int x = (t < 147) ? bsum[t] : 0;
    sm[t] = x;
    __syncthreads();
    for (int off = 1; off < 256; off <<= 1) {
        int y = (t >= off) ? sm[t - off] : 0;
        __syncthreads();
        sm[t] += y;
        __syncthreads();
    }
    if (t < 147) bsum[t] = sm[t] - x;    // exclusive
}

__global__ void k_scan_add(int* __restrict__ rptr, const int* __restrict__ bsum) {
    int i = blockIdx.x * 1024 + threadIdx.x;
    rptr[i] += bsum[blockIdx.x];
}

__global__ void k_scatter(const int* __restrict__ rows, const int* __restrict__ cols,
                          const float* __restrict__ vals,
                          const int* __restrict__ rptr, int* __restrict__ fill,
                          int* __restrict__ colp, float* __restrict__ valp) {
    int t = blockIdx.x * blockDim.x + threadIdx.x;
    if (t >= E_EDGES) return;
    int r = rows[t];
    int pos = rptr[r] + atomicAdd(&fill[r], 1);
    colp[pos] = cols[t];
    valp[pos] = vals[t];
}

// ---- gather SpMM: one wave per row; lane owns 2 columns ----
__global__ void k_spmm(const unsigned short* __restrict__ ego,
                       const int* __restrict__ rptr,
                       const int* __restrict__ colp,
                       const float* __restrict__ valp,
                       float* __restrict__ side) {
    int wid  = (blockIdx.x * blockDim.x + threadIdx.x) >> 6;
    int lane = threadIdx.x & 63;
    if (wid >= N_TOT) return;
    int p0 = rptr[wid], p1 = rptr[wid + 1];
    float a0 = 0.f, a1 = 0.f;
    for (int p = p0; p < p1; ++p) {
        int c = colp[p];                      // wave-uniform -> scalar load
        float v = valp[p];
        unsigned int u = *(const unsigned int*)(ego + (size_t)c * DIM + lane * 2);
        a0 += v * __uint_as_float(u << 16);
        a1 += v * __uint_as_float(u & 0xFFFF0000u);
    }
    float2 st; st.x = a0; st.y = a1;
    *(float2*)(side + (size_t)wid * DIM + lane * 2) = st;
}

// ---- fused dual-GEMM + LeakyReLU + add + L2-normalize epilogue ----
// wave computes 16 rows x 128 cols for both branches via mfma_f32_16x16x32_bf16
__global__ __launch_bounds__(256) void k_gemm(
    const float* __restrict__ side,
    unsigned short* __restrict__ ego,            // read old, write new (in place, per-wave rows)
    const unsigned short* __restrict__ W1,       // bf16 [128][128] row-major (n,k)
    const float* __restrict__ b1,
    const unsigned short* __restrict__ W2,
    const float* __restrict__ b2,
    float* __restrict__ out)                     // pre-offset to this layer's chunk, stride 512
{
    int wave = threadIdx.x >> 6;
    int lane = threadIdx.x & 63;
    int quad = lane >> 4;
    int l16  = lane & 15;
    int i0   = blockIdx.x * 64 + wave * 16;
    int ar   = i0 + l16;                          // A-fragment row (padded buffer: in-bounds)

    f32x4 accS[8], accP[8];
    f32x4 zero = {0.f, 0.f, 0.f, 0.f};
#pragma unroll
    for (int n = 0; n < 8; ++n) { accS[n] = zero; accP[n] = zero; }

    const float*          srow = side + (size_t)ar * DIM;
    const unsigned short* erow = ego  + (size_t)ar * DIM;

#pragma unroll
    for (int s = 0; s < 4; ++s) {
        int k0 = s * 32 + quad * 8;
        float4 f0 = *(const float4*)(srow + k0);
        float4 f1 = *(const float4*)(srow + k0 + 4);
        uint4  eu = *(const uint4*)(erow + k0);

        float sf[8] = {f0.x, f0.y, f0.z, f0.w, f1.x, f1.y, f1.z, f1.w};
        unsigned int ew[4] = {eu.x, eu.y, eu.z, eu.w};

        union { unsigned int u[4]; bf16x8 v; } aS, aP;
#pragma unroll
        for (int j = 0; j < 4; ++j) {
            float elo = __uint_as_float(ew[j] << 16);
            float ehi = __uint_as_float(ew[j] & 0xFFFF0000u);
            aS.u[j] = pack2(sf[2 * j], sf[2 * j + 1]);
            aP.u[j] = pack2(elo * sf[2 * j], ehi * sf[2 * j + 1]);
        }

#pragma unroll
        for (int nt = 0; nt < 8; ++nt) {
            union { uint4 u4; bf16x8 v; } bw1, bw2;
            bw1.u4 = *(const uint4*)(W1 + (size_t)(nt * 16 + l16) * DIM + k0);
            bw2.u4 = *(const uint4*)(W2 + (size_t)(nt * 16 + l16) * DIM + k0);
            accS[nt] = __builtin_amdgcn_mfma_f32_16x16x32_bf16(aS.v, bw1.v, accS[nt], 0, 0, 0);
            accP[nt] = __builtin_amdgcn_mfma_f32_16x16x32_bf16(aP.v, bw2.v, accP[nt], 0, 0, 0);
        }
    }

    // epilogue: bias + leaky + add, then row L2 norm across the 16 lanes of this quad
    float e[8][4];
    float ssum[4] = {0.f, 0.f, 0.f, 0.f};
#pragma unroll
    for (int nt = 0; nt < 8; ++nt) {
        int col = nt * 16 + l16;
        float bb1 = b1[col];
        float bb2 = b2[col];
#pragma unroll
        for (int r = 0; r < 4; ++r) {
            float h1 = accS[nt][r] + bb1; h1 = (h1 >= 0.f) ? h1 : 0.01f * h1;
            float h2 = accP[nt][r] + bb2; h2 = (h2 >= 0.f) ? h2 : 0.01f * h2;
            float ev = h1 + h2;
            e[nt][r] = ev;
            ssum[r] += ev * ev;
        }
    }
#pragma unroll
    for (int r = 0; r < 4; ++r) {
        float s = ssum[r];
        s += __shfl_xor(s, 1);
        s += __shfl_xor(s, 2);
        s += __shfl_xor(s, 4);
        s += __shfl_xor(s, 8);
        float scale = 1.f / fmaxf(sqrtf(s), 1e-12f);
        int gi = i0 + quad * 4 + r;
        if (gi < N_TOT) {
#pragma unroll
            for (int nt = 0; nt < 8; ++nt) {
                int col = nt * 16 + l16;
                out[(size_t)gi * OUT_STRIDE + col] = e[nt][r] * scale;   // f32 output
                ego[(size_t)gi * DIM + col]        = f2bf(e[nt][r]);     // bf16 internal
            }
        }
    }
}

extern "C" void kernel_launch(void* const* d_in, const int* in_sizes, int n_in,
                              void* d_out, int out_size, void* d_ws, size_t ws_size,
                              hipStream_t stream) {
    const float* author = (const float*)d_in[0];
    const float* paper  = (const float*)d_in[1];
    const int*   rows   = (const int*)d_in[2];
    const int*   cols   = (const int*)d_in[3];
    const float* vals   = (const float*)d_in[4];
    const float* W1     = (const float*)d_in[5];
    const float* b1     = (const float*)d_in[6];
    const float* W2     = (const float*)d_in[7];
    const float* b2     = (const float*)d_in[8];
    float* out = (float*)d_out;
    char* ws = (char*)d_ws;

    unsigned short* ego  = (unsigned short*)(ws + EGO_OFF);
    float*          side = (float*)(ws + SIDE_OFF);
    int*            colp = (int*)(ws + COLP_OFF);
    float*          valp = (float*)(ws + VALP_OFF);
    int*            rptr = (int*)(ws + RPTR_OFF);
    int*            cnt  = (int*)(ws + CNT_OFF);
    int*            fill = (int*)(ws + FILL_OFF);
    int*            bsum = (int*)(ws + BSUM_OFF);
    unsigned short* w1b  = (unsigned short*)(ws + W1B_OFF);
    unsigned short* w2b  = (unsigned short*)(ws + W2B_OFF);

    hipMemsetAsync(cnt, 0, N_SCAN * sizeof(int), stream);
    hipMemsetAsync(fill, 0, N_SCAN * sizeof(int), stream);

    k_cvt_w<<<192, 256, 0, stream>>>(W1, W2, w1b, w2b);
    k_init<<<9375, 256, 0, stream>>>(author, paper, ego, out);
    k_hist<<<9375, 256, 0, stream>>>(rows, cnt);
    k_scan_blocks<<<147, 1024, 0, stream>>>(cnt, rptr, bsum);
    k_scan_top<<<1, 256, 0, stream>>>(bsum);
    k_scan_add<<<147, 1024, 0, stream>>>(rptr, bsum);
    k_scatter<<<9375, 256, 0, stream>>>(rows, cols, vals, rptr, fill, colp, valp);

    for (int k = 0; k < 3; ++k) {
        k_spmm<<<(N_TOT * 64 + 255) / 256, 256, 0, stream>>>(ego, rptr, colp, valp, side);
        k_gemm<<<N_ROWPAD / 64, 256, 0, stream>>>(side, ego,
                                                  w1b + (size_t)k * DIM * DIM, b1 + (size_t)k * DIM,
                                                  w2b + (size_t)k * DIM * DIM, b2 + (size_t)k * DIM,
                                                  out + (size_t)(k + 1) * DIM);
    }
}

// Round 4
// 1108.227 us; speedup vs baseline: 1.4195x; 1.4195x over previous
//
#include <hip/hip_runtime.h>
#include <hip/hip_bf16.h>
#include <stdint.h>

#define N_AUTHORS 50000
#define N_PAPERS  100000
#define N_TOT     150000
#define N_ROWPAD  150016      // rows padded to multiple of 64 for GEMM tiles
#define N_SCAN    150528      // 147 * 1024, scan domain
#define DIM       128
#define E_EDGES   2400000
#define OUT_STRIDE 512

// ---- workspace layout (bytes) ----
#define EGO_OFF   0ULL                                   // bf16 [150016][128]  = 38,404,096
#define SIDE_OFF  (EGO_OFF  + 38404096ULL)               // bf16 [150016][128]  = 38,404,096
#define EDGE_OFF  (SIDE_OFF + 38404096ULL)               // u64  [E] (col,val)  = 19,200,000
#define RPTR_OFF  (EDGE_OFF + 19200000ULL)               // int  [150784]       =    603,136
#define CNT_OFF   (RPTR_OFF + 603136ULL)                 // int  [150528]       =    602,112
#define FILL_OFF  (CNT_OFF  + 602112ULL)                 // int  [150528]       =    602,112
#define BSUM_OFF  (FILL_OFF + 602112ULL)                 // int  [256]          =      1,024
#define W1B_OFF   (BSUM_OFF + 1024ULL)                   // bf16 [3][128][128]  =     98,304
#define W2B_OFF   (W1B_OFF  + 98304ULL)                  // bf16 [3][128][128]  =     98,304
// total ~98 MB (fits prior 136.5 MB allocation)

typedef __attribute__((ext_vector_type(8))) __bf16 bf16x8;
typedef __attribute__((ext_vector_type(4))) float  f32x4;

__device__ __forceinline__ unsigned short f2bf(float f) {
    union { float f; unsigned int i; } v; v.f = f;
    unsigned int x = v.i;
    return (unsigned short)((x + 0x7FFFu + ((x >> 16) & 1u)) >> 16);
}
__device__ __forceinline__ unsigned int pack2(float a, float b) {
    return (unsigned int)f2bf(a) | ((unsigned int)f2bf(b) << 16);
}

// ---- convert weights f32 -> bf16 (3*128*128 each) ----
__global__ void k_cvt_w(const float* __restrict__ W1, const float* __restrict__ W2,
                        unsigned short* __restrict__ w1b, unsigned short* __restrict__ w2b) {
    int t = blockIdx.x * blockDim.x + threadIdx.x;
    if (t < 3 * DIM * DIM) {
        w1b[t] = f2bf(W1[t]);
        w2b[t] = f2bf(W2[t]);
    }
}

// ---- build ego = concat(author, paper) as bf16; write layer-0 output chunk (f32 verbatim) ----
__global__ void k_init(const float* __restrict__ author,
                       const float* __restrict__ paper,
                       unsigned short* __restrict__ ego,
                       float* __restrict__ out) {
    int t = blockIdx.x * blockDim.x + threadIdx.x;   // one thread per 8 elements
    if (t >= N_TOT * (DIM / 8)) return;
    int row = t >> 4;        // 16 chunks of 8 per row
    int c   = t & 15;
    const float* src = (row < N_AUTHORS) ? (author + (size_t)row * DIM)
                                         : (paper + (size_t)(row - N_AUTHORS) * DIM);
    float4 a = *(const float4*)(src + c * 8);
    float4 b = *(const float4*)(src + c * 8 + 4);
    float* drow = out + (size_t)row * OUT_STRIDE + c * 8;
    *(float4*)(drow)     = a;
    *(float4*)(drow + 4) = b;
    uint4 v;
    v.x = pack2(a.x, a.y);
    v.y = pack2(a.z, a.w);
    v.z = pack2(b.x, b.y);
    v.w = pack2(b.z, b.w);
    *(uint4*)(ego + (size_t)row * DIM + c * 8) = v;
}

// ---- CSR build ----
__global__ void k_hist(const int* __restrict__ rows, int* __restrict__ cnt) {
    int t = blockIdx.x * blockDim.x + threadIdx.x;
    if (t < E_EDGES) atomicAdd(&cnt[rows[t]], 1);
}

__global__ void k_scan_blocks(const int* __restrict__ cnt, int* __restrict__ rptr,
                              int* __restrict__ bsum) {
    __shared__ int sm[1024];
    int t = threadIdx.x;
    int i = blockIdx.x * 1024 + t;
    int x = cnt[i];
    sm[t] = x;
    __syncthreads();
    for (int off = 1; off < 1024; off <<= 1) {
        int y = (t >= off) ? sm[t - off] : 0;
        __syncthreads();
        sm[t] += y;
        __syncthreads();
    }
    rptr[i] = sm[t] - x;                 // exclusive within block
    if (t == 1023) bsum[blockIdx.x] = sm[1023];
}

__global__ void k_scan_top(int* __restrict__ bsum) {
    __shared__ int sm[256];
    int t = threadIdx.x;
    int x = (t < 147) ? bsum[t] : 0;
    sm[t] = x;
    __syncthreads();
    for (int off = 1; off < 256; off <<= 1) {
        int y = (t >= off) ? sm[t - off] : 0;
        __syncthreads();
        sm[t] += y;
        __syncthreads();
    }
    if (t < 147) bsum[t] = sm[t] - x;    // exclusive
}

__global__ void k_scan_add(int* __restrict__ rptr, const int* __restrict__ bsum) {
    int i = blockIdx.x * 1024 + threadIdx.x;
    rptr[i] += bsum[blockIdx.x];
}

__global__ void k_scatter(const int* __restrict__ rows, const int* __restrict__ cols,
                          const float* __restrict__ vals,
                          const int* __restrict__ rptr, int* __restrict__ fill,
                          unsigned long long* __restrict__ edges) {
    int t = blockIdx.x * blockDim.x + threadIdx.x;
    if (t >= E_EDGES) return;
    int r = rows[t];
    int pos = rptr[r] + atomicAdd(&fill[r], 1);
    unsigned long long e = (unsigned long long)(unsigned int)cols[t]
                         | ((unsigned long long)__float_as_uint(vals[t]) << 32);
    edges[pos] = e;
}

// ---- gather SpMM: one wave per row; lane owns 2 columns; 8 gathers in flight ----
__global__ void k_spmm(const unsigned short* __restrict__ ego,
                       const int* __restrict__ rptr,
                       const unsigned long long* __restrict__ edges,
                       unsigned short* __restrict__ side) {
    int wid  = (blockIdx.x * blockDim.x + threadIdx.x) >> 6;
    int lane = threadIdx.x & 63;
    if (wid >= N_TOT) return;
    int p0 = __builtin_amdgcn_readfirstlane(rptr[wid]);
    int p1 = __builtin_amdgcn_readfirstlane(rptr[wid + 1]);
    int off2 = lane * 2;
    float a0 = 0.f, a1 = 0.f, b0 = 0.f, b1 = 0.f;
    int p = p0;
#define EDGE_DECODE(E, C, V) int C = (int)(unsigned int)(E); float V = __uint_as_float((unsigned int)((E) >> 32))
    for (; p + 8 <= p1; p += 8) {
        unsigned long long e0 = edges[p],     e1 = edges[p + 1],
                           e2 = edges[p + 2], e3 = edges[p + 3],
                           e4 = edges[p + 4], e5 = edges[p + 5],
                           e6 = edges[p + 6], e7 = edges[p + 7];
        EDGE_DECODE(e0, c0, v0); EDGE_DECODE(e1, c1, v1);
        EDGE_DECODE(e2, c2, v2); EDGE_DECODE(e3, c3, v3);
        EDGE_DECODE(e4, c4, v4); EDGE_DECODE(e5, c5, v5);
        EDGE_DECODE(e6, c6, v6); EDGE_DECODE(e7, c7, v7);
        unsigned int u0 = *(const unsigned int*)(ego + (size_t)c0 * DIM + off2);
        unsigned int u1 = *(const unsigned int*)(ego + (size_t)c1 * DIM + off2);
        unsigned int u2 = *(const unsigned int*)(ego + (size_t)c2 * DIM + off2);
        unsigned int u3 = *(const unsigned int*)(ego + (size_t)c3 * DIM + off2);
        unsigned int u4 = *(const unsigned int*)(ego + (size_t)c4 * DIM + off2);
        unsigned int u5 = *(const unsigned int*)(ego + (size_t)c5 * DIM + off2);
        unsigned int u6 = *(const unsigned int*)(ego + (size_t)c6 * DIM + off2);
        unsigned int u7 = *(const unsigned int*)(ego + (size_t)c7 * DIM + off2);
        a0 += v0 * __uint_as_float(u0 << 16); a1 += v0 * __uint_as_float(u0 & 0xFFFF0000u);
        b0 += v1 * __uint_as_float(u1 << 16); b1 += v1 * __uint_as_float(u1 & 0xFFFF0000u);
        a0 += v2 * __uint_as_float(u2 << 16); a1 += v2 * __uint_as_float(u2 & 0xFFFF0000u);
        b0 += v3 * __uint_as_float(u3 << 16); b1 += v3 * __uint_as_float(u3 & 0xFFFF0000u);
        a0 += v4 * __uint_as_float(u4 << 16); a1 += v4 * __uint_as_float(u4 & 0xFFFF0000u);
        b0 += v5 * __uint_as_float(u5 << 16); b1 += v5 * __uint_as_float(u5 & 0xFFFF0000u);
        a0 += v6 * __uint_as_float(u6 << 16); a1 += v6 * __uint_as_float(u6 & 0xFFFF0000u);
        b0 += v7 * __uint_as_float(u7 << 16); b1 += v7 * __uint_as_float(u7 & 0xFFFF0000u);
    }
    for (; p + 2 <= p1; p += 2) {
        unsigned long long e0 = edges[p], e1 = edges[p + 1];
        EDGE_DECODE(e0, c0, v0); EDGE_DECODE(e1, c1, v1);
        unsigned int u0 = *(const unsigned int*)(ego + (size_t)c0 * DIM + off2);
        unsigned int u1 = *(const unsigned int*)(ego + (size_t)c1 * DIM + off2);
        a0 += v0 * __uint_as_float(u0 << 16); a1 += v0 * __uint_as_float(u0 & 0xFFFF0000u);
        b0 += v1 * __uint_as_float(u1 << 16); b1 += v1 * __uint_as_float(u1 & 0xFFFF0000u);
    }
    if (p < p1) {
        unsigned long long e0 = edges[p];
        EDGE_DECODE(e0, c0, v0);
        unsigned int u0 = *(const unsigned int*)(ego + (size_t)c0 * DIM + off2);
        a0 += v0 * __uint_as_float(u0 << 16); a1 += v0 * __uint_as_float(u0 & 0xFFFF0000u);
    }
#undef EDGE_DECODE
    a0 += b0; a1 += b1;
    *(unsigned int*)(side + (size_t)wid * DIM + off2) = pack2(a0, a1);
}

// ---- fused dual-GEMM + LeakyReLU + add + L2-normalize epilogue ----
// wave computes 16 rows x 128 cols for both branches via mfma_f32_16x16x32_bf16
__global__ __launch_bounds__(256) void k_gemm(
    const unsigned short* __restrict__ side,     // bf16 [.][128]
    unsigned short* __restrict__ ego,            // read old, write new (in place, per-wave rows)
    const unsigned short* __restrict__ W1,       // bf16 [128][128] row-major (n,k)
    const float* __restrict__ b1,
    const unsigned short* __restrict__ W2,
    const float* __restrict__ b2,
    float* __restrict__ out)                     // pre-offset to this layer's chunk, stride 512
{
    int wave = threadIdx.x >> 6;
    int lane = threadIdx.x & 63;
    int quad = lane >> 4;
    int l16  = lane & 15;
    int i0   = blockIdx.x * 64 + wave * 16;
    int ar   = i0 + l16;                          // A-fragment row (padded buffer: in-bounds)

    f32x4 accS[8], accP[8];
    f32x4 zero = {0.f, 0.f, 0.f, 0.f};
#pragma unroll
    for (int n = 0; n < 8; ++n) { accS[n] = zero; accP[n] = zero; }

    const unsigned short* srow = side + (size_t)ar * DIM;
    const unsigned short* erow = ego  + (size_t)ar * DIM;

#pragma unroll
    for (int s = 0; s < 4; ++s) {
        int k0 = s * 32 + quad * 8;
        uint4 su = *(const uint4*)(srow + k0);
        uint4 eu = *(const uint4*)(erow + k0);

        unsigned int sw[4] = {su.x, su.y, su.z, su.w};
        unsigned int ew[4] = {eu.x, eu.y, eu.z, eu.w};

        union { unsigned int u[4]; bf16x8 v; } aS, aP;
#pragma unroll
        for (int j = 0; j < 4; ++j) {
            aS.u[j] = sw[j];                       // side already bf16
            float slo = __uint_as_float(sw[j] << 16);
            float shi = __uint_as_float(sw[j] & 0xFFFF0000u);
            float elo = __uint_as_float(ew[j] << 16);
            float ehi = __uint_as_float(ew[j] & 0xFFFF0000u);
            aP.u[j] = pack2(elo * slo, ehi * shi);
        }

#pragma unroll
        for (int nt = 0; nt < 8; ++nt) {
            union { uint4 u4; bf16x8 v; } bw1, bw2;
            bw1.u4 = *(const uint4*)(W1 + (size_t)(nt * 16 + l16) * DIM + k0);
            bw2.u4 = *(const uint4*)(W2 + (size_t)(nt * 16 + l16) * DIM + k0);
            accS[nt] = __builtin_amdgcn_mfma_f32_16x16x32_bf16(aS.v, bw1.v, accS[nt], 0, 0, 0);
            accP[nt] = __builtin_amdgcn_mfma_f32_16x16x32_bf16(aP.v, bw2.v, accP[nt], 0, 0, 0);
        }
    }

    // epilogue: bias + leaky + add, then row L2 norm across the 16 lanes of this quad
    float e[8][4];
    float ssum[4] = {0.f, 0.f, 0.f, 0.f};
#pragma unroll
    for (int nt = 0; nt < 8; ++nt) {
        int col = nt * 16 + l16;
        float bb1 = b1[col];
        float bb2 = b2[col];
#pragma unroll
        for (int r = 0; r < 4; ++r) {
            float h1 = accS[nt][r] + bb1; h1 = (h1 >= 0.f) ? h1 : 0.01f * h1;
            float h2 = accP[nt][r] + bb2; h2 = (h2 >= 0.f) ? h2 : 0.01f * h2;
            float ev = h1 + h2;
            e[nt][r] = ev;
            ssum[r] += ev * ev;
        }
    }
#pragma unroll
    for (int r = 0; r < 4; ++r) {
        float s = ssum[r];
        s += __shfl_xor(s, 1);
        s += __shfl_xor(s, 2);
        s += __shfl_xor(s, 4);
        s += __shfl_xor(s, 8);
        float scale = 1.f / fmaxf(sqrtf(s), 1e-12f);
        int gi = i0 + quad * 4 + r;
        if (gi < N_TOT) {
#pragma unroll
            for (int nt = 0; nt < 8; ++nt) {
                int col = nt * 16 + l16;
                out[(size_t)gi * OUT_STRIDE + col] = e[nt][r] * scale;   // f32 output
                ego[(size_t)gi * DIM + col]        = f2bf(e[nt][r]);     // bf16 internal
            }
        }
    }
}

extern "C" void kernel_launch(void* const* d_in, const int* in_sizes, int n_in,
                              void* d_out, int out_size, void* d_ws, size_t ws_size,
                              hipStream_t stream) {
    const float* author = (const float*)d_in[0];
    const float* paper  = (const float*)d_in[1];
    const int*   rows   = (const int*)d_in[2];
    const int*   cols   = (const int*)d_in[3];
    const float* vals   = (const float*)d_in[4];
    const float* W1     = (const float*)d_in[5];
    const float* b1     = (const float*)d_in[6];
    const float* W2     = (const float*)d_in[7];
    const float* b2     = (const float*)d_in[8];
    float* out = (float*)d_out;
    char* ws = (char*)d_ws;

    unsigned short*     ego   = (unsigned short*)(ws + EGO_OFF);
    unsigned short*     side  = (unsigned short*)(ws + SIDE_OFF);
    unsigned long long* edges = (unsigned long long*)(ws + EDGE_OFF);
    int*                rptr  = (int*)(ws + RPTR_OFF);
    int*                cnt   = (int*)(ws + CNT_OFF);
    int*                fill  = (int*)(ws + FILL_OFF);
    int*                bsum  = (int*)(ws + BSUM_OFF);
    unsigned short*     w1b   = (unsigned short*)(ws + W1B_OFF);
    unsigned short*     w2b   = (unsigned short*)(ws + W2B_OFF);

    hipMemsetAsync(cnt, 0, N_SCAN * sizeof(int), stream);
    hipMemsetAsync(fill, 0, N_SCAN * sizeof(int), stream);

    k_cvt_w<<<192, 256, 0, stream>>>(W1, W2, w1b, w2b);
    k_init<<<9375, 256, 0, stream>>>(author, paper, ego, out);
    k_hist<<<9375, 256, 0, stream>>>(rows, cnt);
    k_scan_blocks<<<147, 1024, 0, stream>>>(cnt, rptr, bsum);
    k_scan_top<<<1, 256, 0, stream>>>(bsum);
    k_scan_add<<<147, 1024, 0, stream>>>(rptr, bsum);
    k_scatter<<<9375, 256, 0, stream>>>(rows, cols, vals, rptr, fill, edges);

    for (int k = 0; k < 3; ++k) {
        k_spmm<<<(N_TOT * 64 + 255) / 256, 256, 0, stream>>>(ego, rptr, edges, side);
        k_gemm<<<N_ROWPAD / 64, 256, 0, stream>>>(side, ego,
                                                  w1b + (size_t)k * DIM * DIM, b1 + (size_t)k * DIM,
                                                  w2b + (size_t)k * DIM * DIM, b2 + (size_t)k * DIM,
                                                  out + (size_t)(k + 1) * DIM);
    }
}